// Round 1
// baseline (555.962 us; speedup 1.0000x reference)
//
#include <hip/hip_runtime.h>

#define NN 512
#define NP (NN*NN)      // 262144 pairs
#define TILES 8         // 16-pair subtiles per block -> 128 pairs per block

// D = H = 64, O0 = O1 = 32
//
// v2 design: radial-specialized waves + swapped GEMMs + no LDS.
//  - 5 waves per block; wave wv computes radial wv for the block's 128 pairs:
//      wv0: radial(x0,f0)->out0_a   wv1: radial(x1,f0)->out0_b
//      wv2: filter1(x0,f11)->out1_a wv3: filter1(x1,f10)->out1_b wv4: filter1(x1,f11)->out1_c
//  - GEMM1 computed swapped: D1[h][p] = W1T·X^T  (A = W1T frag in regs, B = x frag)
//    GEMM2 swapped:          D2[o][p] = W2T·H    (A = W2T frag in regs)
//    -> output lands with p in lanes (l16) and o contiguous along regs -> float4 stores.
//  - H hand-off (D1's row-in-reg layout -> GEMM2's B k-in-lane layout) is a pure
//    cross-quad exchange within each l16 column: 16 ds_bpermute + 8 cndmask, no LDS.
//  - each wave holds ONE weight set in VGPRs (w1f 32 + w2f 16 + b1 16 + b2 8 = 72),
//    so no shared-memory weight staging, no fences, no ds_reads in the main loop.

typedef __bf16 bf16x8 __attribute__((ext_vector_type(8)));
typedef float  f32x4  __attribute__((ext_vector_type(4)));

static __device__ __forceinline__ unsigned pk2(float a, float b) {
    unsigned short ua = __builtin_bit_cast(unsigned short, (__bf16)a);
    unsigned short ub = __builtin_bit_cast(unsigned short, (__bf16)b);
    return (unsigned)ua | ((unsigned)ub << 16);
}

__global__ __launch_bounds__(320, 2) void conv_fused_kernel(
    const float* __restrict__ x0, const float* __restrict__ x1,
    const float* __restrict__ rij,
    const float* __restrict__ w1_0, const float* __restrict__ b1_0,
    const float* __restrict__ w2_0, const float* __restrict__ b2_0,
    const float* __restrict__ w1_1, const float* __restrict__ b1_1,
    const float* __restrict__ w2_1, const float* __restrict__ b2_1,
    const float* __restrict__ w1_2, const float* __restrict__ b1_2,
    const float* __restrict__ w2_2, const float* __restrict__ b2_2,
    float* __restrict__ out)
{
    const int tid = threadIdx.x;
    const int wv  = tid >> 6;    // 0..4 = which radial this wave computes
    const int ln  = tid & 63;
    const int l16 = ln & 15;
    const int q   = ln >> 4;     // quad 0..3

    // per-radial selects (wave-uniform)
    const float* xp  = (wv == 0 || wv == 2) ? x0 : x1;
    const int w = (wv == 3) ? 1 : ((wv >= 2) ? 2 : 0);   // weight set: 0=f0, 1=f10, 2=f11
    const float* w1p = (w == 0) ? w1_0 : ((w == 1) ? w1_1 : w1_2);
    const float* w2p = (w == 0) ? w2_0 : ((w == 1) ? w2_1 : w2_2);
    const float* b1p = (w == 0) ? b1_0 : ((w == 1) ? b1_1 : b1_2);
    const float* b2p = (w == 0) ? b2_0 : ((w == 1) ? b2_1 : b2_2);
    const size_t obase =
        (wv == 0) ? (size_t)0        :
        (wv == 1) ? (size_t)NP *  32 :
        (wv == 2) ? (size_t)NP *  64 :
        (wv == 3) ? (size_t)NP * 160 :
                    (size_t)NP * 256;
    const bool vecout = (wv >= 2);

    // ---- weights -> registers (A-fragments of the swapped GEMMs) ----
    // A-frag layout: lane (q,l16) holds A[row=l16][k=q*8+j], j=0..7.
    // GEMM1 A = W1T[h][k] = w1[k][h]  (w1 is [din=64][dh=64] row-major)
    bf16x8 w1f[4][2];
    #pragma unroll
    for (int nt = 0; nt < 4; ++nt) {
        #pragma unroll
        for (int ks = 0; ks < 2; ++ks) {
            bf16x8 f;
            #pragma unroll
            for (int j = 0; j < 8; ++j)
                f[j] = (__bf16)w1p[(ks*32 + q*8 + j)*64 + nt*16 + l16];
            w1f[nt][ks] = f;
        }
    }
    // GEMM2 A = W2T[o][h] = w2[h][o]  (w2 is [dh=64][dout=32] row-major)
    bf16x8 w2f[2][2];
    #pragma unroll
    for (int nt = 0; nt < 2; ++nt) {
        #pragma unroll
        for (int ks = 0; ks < 2; ++ks) {
            bf16x8 f;
            #pragma unroll
            for (int j = 0; j < 8; ++j)
                f[j] = (__bf16)w2p[(ks*32 + q*8 + j)*32 + nt*16 + l16];
            w2f[nt][ks] = f;
        }
    }
    // biases along the D rows this lane owns: row = nt*16 + q*4 + r
    float b1r[4][4], b2r[2][4];
    #pragma unroll
    for (int nt = 0; nt < 4; ++nt)
        #pragma unroll
        for (int r = 0; r < 4; ++r) b1r[nt][r] = b1p[nt*16 + q*4 + r];
    #pragma unroll
    for (int nt = 0; nt < 2; ++nt)
        #pragma unroll
        for (int r = 0; r < 4; ++r) b2r[nt][r] = b2p[nt*16 + q*4 + r];

    // cross-quad exchange addresses: pull from lanes (2(q&1))*16+l16 and +16
    const int addrA = ((q & 1) * 32 + l16) * 4;
    const int addrB = addrA + 64;
    const bool hiq = (q >= 2);

    for (int t = 0; t < TILES; ++t) {
        const int p0 = blockIdx.x * (16 * TILES) + t * 16;
        const int p  = p0 + l16;

        // x fragment (B operand of GEMM1): lane holds X[p][ks*32+q*8+j]
        bf16x8 ax[2];
        {
            const float* xr = xp + (size_t)p * 64 + q * 8;
            #pragma unroll
            for (int ks = 0; ks < 2; ++ks) {
                float4 v0 = *(const float4*)(xr + ks * 32);
                float4 v1 = *(const float4*)(xr + ks * 32 + 4);
                bf16x8 a;
                a[0]=(__bf16)v0.x; a[1]=(__bf16)v0.y; a[2]=(__bf16)v0.z; a[3]=(__bf16)v0.w;
                a[4]=(__bf16)v1.x; a[5]=(__bf16)v1.y; a[6]=(__bf16)v1.z; a[7]=(__bf16)v1.w;
                ax[ks] = a;
            }
        }

        // unit vector for this lane's pair (all quads redundantly; broadcast-friendly)
        float u0 = 0.f, u1 = 0.f, u2 = 0.f;
        if (vecout) {
            const float* rp = rij + (size_t)p * 3;
            float r0 = rp[0], r1 = rp[1], r2 = rp[2];
            float s  = r0*r0 + r1*r1 + r2*r2;
            float inv = (s < 1e-16f) ? 0.0f : (1.0f / sqrtf(fmaxf(s, 1e-8f)));
            u0 = r0 * inv; u1 = r1 * inv; u2 = r2 * inv;
        }

        // ---- GEMM1 swapped: D1[h][p] = W1T · X^T  (lane: col p=l16, rows h=nt*16+q*4+r) ----
        f32x4 acc1[4];
        #pragma unroll
        for (int nt = 0; nt < 4; ++nt) acc1[nt] = (f32x4){0.f, 0.f, 0.f, 0.f};
        #pragma unroll
        for (int nt = 0; nt < 4; ++nt) {
            #pragma unroll
            for (int ks = 0; ks < 2; ++ks)
                acc1[nt] = __builtin_amdgcn_mfma_f32_16x16x32_bf16(
                    w1f[nt][ks], ax[ks], acc1[nt], 0, 0, 0);
        }

        // bias + relu, pack pairs (r0,r1) and (r2,r3) as 2xbf16 dwords per nt-tile
        unsigned dw01[4], dw23[4];
        #pragma unroll
        for (int nt = 0; nt < 4; ++nt) {
            float h0 = fmaxf(acc1[nt][0] + b1r[nt][0], 0.f);
            float h1 = fmaxf(acc1[nt][1] + b1r[nt][1], 0.f);
            float h2 = fmaxf(acc1[nt][2] + b1r[nt][2], 0.f);
            float h3 = fmaxf(acc1[nt][3] + b1r[nt][3], 0.f);
            dw01[nt] = pk2(h0, h1);
            dw23[nt] = pk2(h2, h3);
        }

        // ---- cross-quad exchange + GEMM2 swapped: D2[o][p] = W2T · H ----
        // target lane (q,l16) elem j needs H[ks*32+q*8+j][l16]:
        //   src lane = (2(q&1)+(j>>2))*16 + l16, reg r=j&3, tile nt = ks*2+(q>>1)
        f32x4 acc2[2];
        acc2[0] = (f32x4){0.f, 0.f, 0.f, 0.f};
        acc2[1] = (f32x4){0.f, 0.f, 0.f, 0.f};
        #pragma unroll
        for (int ks = 0; ks < 2; ++ks) {
            const int n0 = ks*2, n1 = ks*2 + 1;
            int d0a = __builtin_amdgcn_ds_bpermute(addrA, (int)dw01[n0]);
            int d0b = __builtin_amdgcn_ds_bpermute(addrA, (int)dw01[n1]);
            int d1a = __builtin_amdgcn_ds_bpermute(addrA, (int)dw23[n0]);
            int d1b = __builtin_amdgcn_ds_bpermute(addrA, (int)dw23[n1]);
            int d2a = __builtin_amdgcn_ds_bpermute(addrB, (int)dw01[n0]);
            int d2b = __builtin_amdgcn_ds_bpermute(addrB, (int)dw01[n1]);
            int d3a = __builtin_amdgcn_ds_bpermute(addrB, (int)dw23[n0]);
            int d3b = __builtin_amdgcn_ds_bpermute(addrB, (int)dw23[n1]);
            int4 dv;
            dv.x = hiq ? d0b : d0a;
            dv.y = hiq ? d1b : d1a;
            dv.z = hiq ? d2b : d2a;
            dv.w = hiq ? d3b : d3a;
            bf16x8 pf = __builtin_bit_cast(bf16x8, dv);
            #pragma unroll
            for (int nt = 0; nt < 2; ++nt)
                acc2[nt] = __builtin_amdgcn_mfma_f32_16x16x32_bf16(
                    w2f[nt][ks], pf, acc2[nt], 0, 0, 0);
        }

        // ---- epilogue: lane holds o = nt*16+q*4+r (contiguous in r), p = l16 ----
        if (!vecout) {
            // out0: [p][32] -> one float4 per nt
            #pragma unroll
            for (int nt = 0; nt < 2; ++nt) {
                f32x4 v;
                #pragma unroll
                for (int r = 0; r < 4; ++r) v[r] = acc2[nt][r] + b2r[nt][r];
                *(f32x4*)(out + obase + (size_t)p * 32 + nt*16 + q*4) = v;
            }
        } else {
            // out1: [p][32][3] -> 12 contiguous floats per nt = 3 float4
            #pragma unroll
            for (int nt = 0; nt < 2; ++nt) {
                float rv0 = acc2[nt][0] + b2r[nt][0];
                float rv1 = acc2[nt][1] + b2r[nt][1];
                float rv2 = acc2[nt][2] + b2r[nt][2];
                float rv3 = acc2[nt][3] + b2r[nt][3];
                f32x4 va = {rv0*u0, rv0*u1, rv0*u2, rv1*u0};
                f32x4 vb = {rv1*u1, rv1*u2, rv2*u0, rv2*u1};
                f32x4 vc = {rv2*u2, rv3*u0, rv3*u1, rv3*u2};
                float* op = out + obase + ((size_t)p * 32 + nt*16 + q*4) * 3;
                *(f32x4*)(op + 0) = va;
                *(f32x4*)(op + 4) = vb;
                *(f32x4*)(op + 8) = vc;
            }
        }
    }
}

extern "C" void kernel_launch(void* const* d_in, const int* in_sizes, int n_in,
                              void* d_out, int out_size, void* d_ws, size_t ws_size,
                              hipStream_t stream) {
    const float* x0   = (const float*)d_in[0];
    const float* x1   = (const float*)d_in[1];
    // d_in[2] = rbf : unused by the reference
    const float* rij  = (const float*)d_in[3];

    conv_fused_kernel<<<NP / (16 * TILES), 320, 0, stream>>>(
        x0, x1, rij,
        (const float*)d_in[4],  (const float*)d_in[5],  (const float*)d_in[6],  (const float*)d_in[7],   // f0
        (const float*)d_in[8],  (const float*)d_in[9],  (const float*)d_in[10], (const float*)d_in[11],  // f10
        (const float*)d_in[12], (const float*)d_in[13], (const float*)d_in[14], (const float*)d_in[15],  // f11
        (float*)d_out);
}

// Round 2
// 518.463 us; speedup vs baseline: 1.0723x; 1.0723x over previous
//
#include <hip/hip_runtime.h>

#define NN 512
#define NP (NN*NN)      // 262144 pairs
// D = H = 64, O0 = O1 = 32

typedef __bf16 bf16x8 __attribute__((ext_vector_type(8)));
typedef float  f32x4  __attribute__((ext_vector_type(4)));

// Radial schedule: {x-select, weight-select, is-vector-output}
//  rd0: radial(x0,f0)  -> out0_a   rd1: radial(x1,f0)  -> out0_b
//  rd2: filter1(x0,f11)-> out1_a   rd3: filter1(x1,f10)-> out1_b
//  rd4: filter1(x1,f11)-> out1_c

__global__ __launch_bounds__(256) void conv_fused_kernel(
    const float* __restrict__ x0, const float* __restrict__ x1,
    const float* __restrict__ rij,
    const float* __restrict__ w1_0, const float* __restrict__ b1_0,
    const float* __restrict__ w2_0, const float* __restrict__ b2_0,
    const float* __restrict__ w1_1, const float* __restrict__ b1_1,
    const float* __restrict__ w2_1, const float* __restrict__ b2_1,
    const float* __restrict__ w1_2, const float* __restrict__ b1_2,
    const float* __restrict__ w2_2, const float* __restrict__ b2_2,
    float* __restrict__ out)
{
    // Weights transposed (so B-frags are 8 contiguous k per lane -> ds_read_b128),
    // rows padded to 72 elems (144 B, 16B-divisible so vector reads stay aligned).
    __shared__ __attribute__((aligned(16))) __bf16 sW1T[3][64][72]; // [w][dh][din]
    __shared__ __attribute__((aligned(16))) __bf16 sW2T[3][32][72]; // [w][dout][dh]
    __shared__ float sB1[3][64];
    __shared__ float sB2[3][32];
    __shared__ __attribute__((aligned(16))) __bf16 sH[4][16][72];   // per-wave H round-trip
    __shared__ float sU[4][16][4];                                  // per-wave unit vectors

    const int tid = threadIdx.x;
    const int wv  = tid >> 6;   // wave id 0..3
    const int ln  = tid & 63;   // lane
    const int l16 = ln & 15;
    const int q   = ln >> 4;    // quad 0..3

    // ---- stage weights (once per block; reads are L2/L3 hits across blocks) ----
    {
        const float* w1s[3] = {w1_0, w1_1, w1_2};
        const float* w2s[3] = {w2_0, w2_1, w2_2};
        const float* b1s[3] = {b1_0, b1_1, b1_2};
        const float* b2s[3] = {b2_0, b2_1, b2_2};
        for (int w = 0; w < 3; ++w) {
            for (int e = tid; e < 64*64; e += 256) {
                int k = e >> 6, n = e & 63;              // w1 is [din][dh] row-major
                sW1T[w][n][k] = (__bf16)w1s[w][e];
            }
            for (int e = tid; e < 64*32; e += 256) {
                int k = e >> 5, n = e & 31;              // w2 is [dh][dout]
                sW2T[w][n][k] = (__bf16)w2s[w][e];
            }
            if (tid < 64) sB1[w][tid] = b1s[w][tid];
            if (tid < 32) sB2[w][tid] = b2s[w][tid];
        }
    }
    __syncthreads();

    const size_t OB0a = 0;
    const size_t OB0b = (size_t)NP * 32;
    const size_t OB1a = (size_t)NP * 64;
    const size_t OB1b = OB1a + (size_t)NP * 96;
    const size_t OB1c = OB1b + (size_t)NP * 96;

    const int xsel[5]    = {0, 1, 0, 1, 1};
    const int wsel[5]    = {0, 0, 2, 1, 2};
    const size_t obase[5] = {OB0a, OB0b, OB1a, OB1b, OB1c};

    // 4 m-tiles of 16 pairs per wave -> 256 pairs per block
    for (int t = 0; t < 4; ++t) {
        const int p0 = blockIdx.x * 256 + (t * 4 + wv) * 16;

        // unit vectors (mask for dij<EPS folded in): lanes 0..15, one row each
        if (ln < 16) {
            const float* rp = rij + (size_t)(p0 + ln) * 3;
            float r0 = rp[0], r1 = rp[1], r2 = rp[2];
            float s  = r0*r0 + r1*r1 + r2*r2;
            float inv = (s < 1e-16f) ? 0.0f : (1.0f / sqrtf(fmaxf(s, 1e-8f)));
            sU[wv][ln][0] = r0 * inv;
            sU[wv][ln][1] = r1 * inv;
            sU[wv][ln][2] = r2 * inv;
        }

        // A-fragments for x0 and x1 (reused across radials)
        // lane holds X[p0 + l16][ks*32 + q*8 + j], j=0..7
        bf16x8 ax[2][2];
        {
            const float* xs[2] = {x0, x1};
            #pragma unroll
            for (int xi = 0; xi < 2; ++xi) {
                const float* xr = xs[xi] + (size_t)(p0 + l16) * 64 + q * 8;
                #pragma unroll
                for (int ks = 0; ks < 2; ++ks) {
                    float4 v0 = *(const float4*)(xr + ks * 32);
                    float4 v1 = *(const float4*)(xr + ks * 32 + 4);
                    bf16x8 a;
                    a[0] = (__bf16)v0.x; a[1] = (__bf16)v0.y;
                    a[2] = (__bf16)v0.z; a[3] = (__bf16)v0.w;
                    a[4] = (__bf16)v1.x; a[5] = (__bf16)v1.y;
                    a[6] = (__bf16)v1.z; a[7] = (__bf16)v1.w;
                    ax[xi][ks] = a;
                }
            }
        }

        // sU visible to whole wave (same-wave DS is in-order; fence stops compiler reorder)
        asm volatile("s_waitcnt lgkmcnt(0)" ::: "memory");

        for (int rd = 0; rd < 5; ++rd) {
            const int w = wsel[rd];

            // ---- GEMM1: H = relu(X @ W1 + b1), 16x64 ----
            f32x4 acc[4];
            #pragma unroll
            for (int nt = 0; nt < 4; ++nt) acc[nt] = (f32x4){0.f, 0.f, 0.f, 0.f};
            #pragma unroll
            for (int nt = 0; nt < 4; ++nt) {
                #pragma unroll
                for (int ks = 0; ks < 2; ++ks) {
                    bf16x8 b = *(const bf16x8*)&sW1T[w][nt * 16 + l16][ks * 32 + q * 8];
                    acc[nt] = __builtin_amdgcn_mfma_f32_16x16x32_bf16(
                        ax[xsel[rd]][ks], b, acc[nt], 0, 0, 0);
                }
            }
            // bias + relu, write H to LDS in row-major (C-layout -> memory)
            #pragma unroll
            for (int nt = 0; nt < 4; ++nt) {
                float bb = sB1[w][nt * 16 + l16];
                #pragma unroll
                for (int r = 0; r < 4; ++r) {
                    float h = fmaxf(acc[nt][r] + bb, 0.0f);
                    sH[wv][q * 4 + r][nt * 16 + l16] = (__bf16)h;
                }
            }
            asm volatile("s_waitcnt lgkmcnt(0)" ::: "memory");

            // H back as A-fragments
            bf16x8 h2[2];
            h2[0] = *(const bf16x8*)&sH[wv][l16][q * 8];
            h2[1] = *(const bf16x8*)&sH[wv][l16][32 + q * 8];

            // ---- GEMM2: RAD = H @ W2 + b2, 16x32 ----
            f32x4 acc2[2];
            acc2[0] = (f32x4){0.f, 0.f, 0.f, 0.f};
            acc2[1] = (f32x4){0.f, 0.f, 0.f, 0.f};
            #pragma unroll
            for (int nt = 0; nt < 2; ++nt) {
                #pragma unroll
                for (int ks = 0; ks < 2; ++ks) {
                    bf16x8 b = *(const bf16x8*)&sW2T[w][nt * 16 + l16][ks * 32 + q * 8];
                    acc2[nt] = __builtin_amdgcn_mfma_f32_16x16x32_bf16(
                        h2[ks], b, acc2[nt], 0, 0, 0);
                }
            }

            // ---- epilogue ----
            if (rd < 2) {
                // out0: [p][o]
                #pragma unroll
                for (int nt = 0; nt < 2; ++nt) {
                    float bb = sB2[w][nt * 16 + l16];
                    #pragma unroll
                    for (int r = 0; r < 4; ++r) {
                        int p = p0 + q * 4 + r;
                        out[obase[rd] + (size_t)p * 32 + nt * 16 + l16] = acc2[nt][r] + bb;
                    }
                }
            } else {
                // out1: [p][o][3] = u[p][c] * rad[p][o]
                #pragma unroll
                for (int nt = 0; nt < 2; ++nt) {
                    float bb = sB2[w][nt * 16 + l16];
                    #pragma unroll
                    for (int r = 0; r < 4; ++r) {
                        int pr = q * 4 + r;
                        int p  = p0 + pr;
                        float rv = acc2[nt][r] + bb;
                        size_t base = obase[rd] + ((size_t)p * 32 + nt * 16 + l16) * 3;
                        out[base + 0] = rv * sU[wv][pr][0];
                        out[base + 1] = rv * sU[wv][pr][1];
                        out[base + 2] = rv * sU[wv][pr][2];
                    }
                }
            }
            // next radial's sH writes are issued after this radial's sH reads:
            // same-wave DS pipe is in-order, asm fences prevent compiler reordering.
        }
    }
}

extern "C" void kernel_launch(void* const* d_in, const int* in_sizes, int n_in,
                              void* d_out, int out_size, void* d_ws, size_t ws_size,
                              hipStream_t stream) {
    const float* x0   = (const float*)d_in[0];
    const float* x1   = (const float*)d_in[1];
    // d_in[2] = rbf : unused by the reference
    const float* rij  = (const float*)d_in[3];

    conv_fused_kernel<<<NP / 256, 256, 0, stream>>>(
        x0, x1, rij,
        (const float*)d_in[4],  (const float*)d_in[5],  (const float*)d_in[6],  (const float*)d_in[7],   // f0
        (const float*)d_in[8],  (const float*)d_in[9],  (const float*)d_in[10], (const float*)d_in[11],  // f10
        (const float*)d_in[12], (const float*)d_in[13], (const float*)d_in[14], (const float*)d_in[15],  // f11
        (float*)d_out);
}